// Round 5
// baseline (663.821 us; speedup 1.0000x reference)
//
#include <hip/hip_runtime.h>

#define NN 50000
#define NE 800000
#define NIN 32
#define EIN 16
#define HID 128
#define NL 3
#define NG 256
#define TE 64
#define BM 64   // kMlp row tile
#define SCAN_B 196  // ceil(NN/256)

typedef unsigned short ushort_t;
typedef __attribute__((ext_vector_type(8))) _Float16 half8;
typedef __attribute__((ext_vector_type(4))) float f32x4;
typedef __attribute__((ext_vector_type(2))) __fp16 h2;

__device__ __forceinline__ unsigned pkf16(float a, float b){
  h2 h = __builtin_amdgcn_cvt_pkrtz(a, b);
  union{ h2 h; unsigned u; } c; c.h = h; return c.u;
}
__device__ __forceinline__ h2 u2h(unsigned u){
  union{ unsigned u; h2 h; } c; c.u = u; return c.h;
}
__device__ __forceinline__ ushort_t f2h(float x){
  union{ __fp16 h; ushort_t u; } c; c.h = (__fp16)x; return c.u;
}
__device__ __forceinline__ float h2f(ushort_t v){
  union{ ushort_t u; __fp16 h; } c; c.u = v; return (float)c.h;
}

typedef const __attribute__((address_space(1))) unsigned gas_t;
typedef __attribute__((address_space(3))) unsigned las_t;
__device__ __forceinline__ void stage16(const void* g, void* l){
  __builtin_amdgcn_global_load_lds((gas_t*)g, (las_t*)l, 16, 0, 0);
}

// ======================= CSR build (dst-sorted) =======================
__global__ void kZero(int* __restrict__ p, int n){
  int i = blockIdx.x*256 + threadIdx.x;
  if (i < n) p[i] = 0;
}

__global__ void kHist(const int* __restrict__ dst, int* __restrict__ cnt){
  int e = blockIdx.x*256 + threadIdx.x;
  if (e < NE) atomicAdd(&cnt[dst[e]], 1);
}

__global__ void kPartSum(const int* __restrict__ cnt, int* __restrict__ psum){
  __shared__ int sm[256];
  int b = blockIdx.x, t = threadIdx.x, i = b*256 + t;
  sm[t] = (i < NN) ? cnt[i] : 0;
  __syncthreads();
  for (int o = 128; o > 0; o >>= 1){
    if (t < o) sm[t] += sm[t + o];
    __syncthreads();
  }
  if (t == 0) psum[b] = sm[0];
}

__global__ __launch_bounds__(256) void kScanPart(const int* __restrict__ psum,
                                                 int* __restrict__ pofs, int* __restrict__ offs){
  __shared__ int sm[256];
  int t = threadIdx.x;
  int v = (t < SCAN_B) ? psum[t] : 0;
  sm[t] = v;
  __syncthreads();
  for (int o = 1; o < 256; o <<= 1){
    int x = (t >= o) ? sm[t - o] : 0;
    __syncthreads();
    sm[t] += x;
    __syncthreads();
  }
  if (t < SCAN_B) pofs[t] = sm[t] - v;
  if (t == 255) offs[NN] = sm[255];
}

__global__ void kScanApply(const int* __restrict__ cnt, const int* __restrict__ pofs,
                           int* __restrict__ offs, int* __restrict__ curs){
  __shared__ int sm[256];
  int b = blockIdx.x, t = threadIdx.x, i = b*256 + t;
  int v = (i < NN) ? cnt[i] : 0;
  sm[t] = v;
  __syncthreads();
  for (int o = 1; o < 256; o <<= 1){
    int x = (t >= o) ? sm[t - o] : 0;
    __syncthreads();
    sm[t] += x;
    __syncthreads();
  }
  int ex = sm[t] - v + pofs[b];
  if (i < NN){ offs[i] = ex; curs[i] = ex; }
}

__global__ void kScatter(const int* __restrict__ dst, const int* __restrict__ src,
                         int* __restrict__ curs, int* __restrict__ perm, int* __restrict__ srcPos){
  int e = blockIdx.x*256 + threadIdx.x;
  if (e < NE){
    int p = atomicAdd(&curs[dst[e]], 1);
    perm[p] = e;
    srcPos[p] = src[e];
  }
}

// eattr rows permuted to CSR order, packed f16 pairs
__global__ void kPermEA(const float* __restrict__ eattr, const int* __restrict__ perm,
                        unsigned* __restrict__ eaPos){
  int gid = blockIdx.x*256 + threadIdx.x;   // NE*2
  if (gid >= NE*2) return;
  int p = gid >> 1, part = gid & 1;
  int e = perm[p];
  const float* row = eattr + (size_t)e*EIN + part*8;
  float4 v0 = *(const float4*)row;
  float4 v1 = *(const float4*)(row + 4);
  uint4 d;
  d.x = pkf16(v0.x, v0.y); d.y = pkf16(v0.z, v0.w);
  d.z = pkf16(v1.x, v1.y); d.w = pkf16(v1.z, v1.w);
  *(uint4*)&eaPos[(size_t)p*8 + part*4] = d;
}

// ======================= W -> f16, transposed + pre-swizzled; zero zb tail =======================
__global__ void kConvW(const float* __restrict__ w1, const float* __restrict__ w2,
                       ushort_t* __restrict__ wtb, ushort_t* __restrict__ zb){
  int gid = blockIdx.x*256 + threadIdx.x;
  if (gid < 6*16384){
    int mat = gid >> 14, idx = gid & 16383;
    int k = idx >> 7, n = idx & 127;
    const float* src = (mat < 3) ? (w1 + (size_t)mat*16384) : (w2 + (size_t)(mat-3)*16384);
    wtb[(size_t)mat*16384 + n*128 + (k ^ ((n&7)<<3))] = f2h(src[idx]);
  } else {
    int t = gid - 6*16384;
    if (t < 48*128) zb[(size_t)NN*HID + t] = 0;
  }
}

// ======================= node embed -> hf (f16) =======================
__global__ void kNodeInit(const float* __restrict__ x, const float* __restrict__ w,
                          const float* __restrict__ b, ushort_t* __restrict__ hf){
  int gid = blockIdx.x*256 + threadIdx.x;   // NN*64
  if (gid >= NN*64) return;
  int n = gid >> 6, c = (gid & 63)*2;
  const float* xr = x + (size_t)n*NIN;
  float a0 = b[c], a1 = b[c+1];
  #pragma unroll
  for (int k = 0; k < NIN; ++k){
    float xv = xr[k];
    a0 = fmaf(xv, w[k*HID + c],     a0);
    a1 = fmaf(xv, w[k*HID + c + 1], a1);
  }
  *(unsigned*)&hf[(size_t)n*HID + c] = pkf16(a0, a1);
}

// ======================= GINE aggregate: wave-per-node, scalar edge data =======================
// Edge loop index p is wave-uniform (readfirstlane'd CSR bounds) -> eaPos/srcPos loads are
// uniform-address (SMEM-selectable); f16 splats built on the scalar pipe (u&0xffff)*0x10001.
__device__ __forceinline__ void edgeF16(int p, const unsigned* __restrict__ eaPos,
    const int* __restrict__ srcPos, const ushort_t* __restrict__ hf, int c0,
    const h2* wP, h2 bias, float& acc0, float& acc1){
  const uint4* ep4 = (const uint4*)(eaPos + (size_t)p*8);
  uint4 ea0 = ep4[0], ea1 = ep4[1];
  int s = srcPos[p];
  unsigned hs = *(const unsigned*)&hf[(size_t)s*HID + c0];
  h2 a = bias;
  a = __builtin_elementwise_fma(u2h((ea0.x & 0xffffu)*0x10001u), wP[0],  a);
  a = __builtin_elementwise_fma(u2h((ea0.x >> 16)    *0x10001u), wP[1],  a);
  a = __builtin_elementwise_fma(u2h((ea0.y & 0xffffu)*0x10001u), wP[2],  a);
  a = __builtin_elementwise_fma(u2h((ea0.y >> 16)    *0x10001u), wP[3],  a);
  a = __builtin_elementwise_fma(u2h((ea0.z & 0xffffu)*0x10001u), wP[4],  a);
  a = __builtin_elementwise_fma(u2h((ea0.z >> 16)    *0x10001u), wP[5],  a);
  a = __builtin_elementwise_fma(u2h((ea0.w & 0xffffu)*0x10001u), wP[6],  a);
  a = __builtin_elementwise_fma(u2h((ea0.w >> 16)    *0x10001u), wP[7],  a);
  a = __builtin_elementwise_fma(u2h((ea1.x & 0xffffu)*0x10001u), wP[8],  a);
  a = __builtin_elementwise_fma(u2h((ea1.x >> 16)    *0x10001u), wP[9],  a);
  a = __builtin_elementwise_fma(u2h((ea1.y & 0xffffu)*0x10001u), wP[10], a);
  a = __builtin_elementwise_fma(u2h((ea1.y >> 16)    *0x10001u), wP[11], a);
  a = __builtin_elementwise_fma(u2h((ea1.z & 0xffffu)*0x10001u), wP[12], a);
  a = __builtin_elementwise_fma(u2h((ea1.z >> 16)    *0x10001u), wP[13], a);
  a = __builtin_elementwise_fma(u2h((ea1.w & 0xffffu)*0x10001u), wP[14], a);
  a = __builtin_elementwise_fma(u2h((ea1.w >> 16)    *0x10001u), wP[15], a);
  h2 t = u2h(hs) + a;
  h2 zz; zz[0] = (__fp16)0.f; zz[1] = (__fp16)0.f;
  t = __builtin_elementwise_max(t, zz);
  acc0 += (float)t[0];
  acc1 += (float)t[1];
}

__global__ __launch_bounds__(256) void kAgg(
    const ushort_t* __restrict__ hf, const unsigned* __restrict__ eaPos,
    const int* __restrict__ srcPos, const int* __restrict__ offs,
    const float* __restrict__ Wl, const float* __restrict__ bl,
    const float* __restrict__ epsArr, int layer,
    ushort_t* __restrict__ zb, float* __restrict__ bnS, float* __restrict__ bnQ){
  int tid = threadIdx.x, lane = tid & 63, wv = tid >> 6;
  if (blockIdx.x == 0 && tid < 128){ bnS[tid] = 0.f; bnQ[tid] = 0.f; }
  int c0 = 2*lane;
  h2 wP[EIN];
  #pragma unroll
  for (int k = 0; k < EIN; ++k)
    wP[k] = __builtin_amdgcn_cvt_pkrtz(Wl[k*HID + c0], Wl[k*HID + c0 + 1]);
  h2 bias = __builtin_amdgcn_cvt_pkrtz(bl[c0], bl[c0+1]);
  float ep1 = 1.f + epsArr[layer];
  int gw = blockIdx.x*4 + wv, nwv = gridDim.x*4;
  for (int n = gw; n < NN; n += nwv){
    int s0 = __builtin_amdgcn_readfirstlane(offs[n]);
    int s1 = __builtin_amdgcn_readfirstlane(offs[n+1]);
    float acc0 = 0.f, acc1 = 0.f;
    int p = s0;
    for (; p + 1 < s1; p += 2){
      edgeF16(p,     eaPos, srcPos, hf, c0, wP, bias, acc0, acc1);
      edgeF16(p + 1, eaPos, srcPos, hf, c0, wP, bias, acc0, acc1);
    }
    if (p < s1) edgeF16(p, eaPos, srcPos, hf, c0, wP, bias, acc0, acc1);
    unsigned hw = *(const unsigned*)&hf[(size_t)n*HID + c0];
    h2 hv = u2h(hw);
    float z0v = ep1 * (float)hv[0] + acc0;
    float z1v = ep1 * (float)hv[1] + acc1;
    *(unsigned*)&zb[(size_t)n*HID + (c0 ^ ((n & 7) << 3))] = pkf16(z0v, z1v);
  }
}

// ======================= fused MLP via MFMA (f16) =======================
__global__ __launch_bounds__(256, 1) void kMlp(
    const ushort_t* __restrict__ zb, float* __restrict__ z2,
    const ushort_t* __restrict__ w1t, const float* __restrict__ b1,
    const ushort_t* __restrict__ w2t, const float* __restrict__ b2,
    float* __restrict__ bnS, float* __restrict__ bnQ){
  __shared__ __align__(16) ushort_t As[BM*128];
  __shared__ __align__(16) ushort_t Bs[128*128];
  __shared__ float red[256];
  int tid  = threadIdx.x;
  int lane = tid & 63;
  int w    = tid >> 6;
  int ln   = tid & 15;
  int q    = (tid >> 4) & 3;
  int rbase = blockIdx.x * BM;
  int m0 = (w >> 1) * 32;
  int wc = (w & 1) * 64;

  const char* gA = (const char*)(zb + (size_t)rbase * HID);
  #pragma unroll
  for (int it = 0; it < 4; ++it)
    stage16(gA + (w*4096 + it*1024 + lane*16), (char*)As + (w*4096 + it*1024));
  const char* gB1 = (const char*)w1t;
  #pragma unroll
  for (int it = 0; it < 8; ++it)
    stage16(gB1 + (w*8192 + it*1024 + lane*16), (char*)Bs + (w*8192 + it*1024));
  __syncthreads();

  f32x4 acc[2][4];
  #pragma unroll
  for (int i = 0; i < 2; ++i)
    #pragma unroll
    for (int j = 0; j < 4; ++j) acc[i][j] = (f32x4)0.f;

  #pragma unroll
  for (int kk = 0; kk < 4; ++kk){
    int kb = kk*32 + q*8;
    half8 af[2], bf[4];
    #pragma unroll
    for (int i = 0; i < 2; ++i){
      int m = m0 + 16*i + ln;
      af[i] = *(const half8*)&As[m*128 + (kb ^ ((m&7)<<3))];
    }
    #pragma unroll
    for (int j = 0; j < 4; ++j){
      int nn = wc + 16*j + ln;
      bf[j] = *(const half8*)&Bs[nn*128 + (kb ^ ((nn&7)<<3))];
    }
    #pragma unroll
    for (int i = 0; i < 2; ++i)
      #pragma unroll
      for (int j = 0; j < 4; ++j)
        acc[i][j] = __builtin_amdgcn_mfma_f32_16x16x32_f16(af[i], bf[j], acc[i][j], 0, 0, 0);
  }
  __syncthreads();

  const char* gB2 = (const char*)w2t;
  #pragma unroll
  for (int it = 0; it < 8; ++it)
    stage16(gB2 + (w*8192 + it*1024 + lane*16), (char*)Bs + (w*8192 + it*1024));
  {
    float b1v[4];
    #pragma unroll
    for (int j = 0; j < 4; ++j) b1v[j] = b1[wc + 16*j + ln];
    #pragma unroll
    for (int i = 0; i < 2; ++i){
      #pragma unroll
      for (int j = 0; j < 4; ++j){
        int kc = wc + 16*j + ln;
        #pragma unroll
        for (int r = 0; r < 4; ++r){
          int m = m0 + 16*i + 4*q + r;
          As[m*128 + (kc ^ ((m&7)<<3))] = f2h(fmaxf(acc[i][j][r] + b1v[j], 0.f));
        }
      }
    }
  }
  #pragma unroll
  for (int i = 0; i < 2; ++i)
    #pragma unroll
    for (int j = 0; j < 4; ++j) acc[i][j] = (f32x4)0.f;
  __syncthreads();

  #pragma unroll
  for (int kk = 0; kk < 4; ++kk){
    int kb = kk*32 + q*8;
    half8 af[2], bf[4];
    #pragma unroll
    for (int i = 0; i < 2; ++i){
      int m = m0 + 16*i + ln;
      af[i] = *(const half8*)&As[m*128 + (kb ^ ((m&7)<<3))];
    }
    #pragma unroll
    for (int j = 0; j < 4; ++j){
      int nn = wc + 16*j + ln;
      bf[j] = *(const half8*)&Bs[nn*128 + (kb ^ ((nn&7)<<3))];
    }
    #pragma unroll
    for (int i = 0; i < 2; ++i)
      #pragma unroll
      for (int j = 0; j < 4; ++j)
        acc[i][j] = __builtin_amdgcn_mfma_f32_16x16x32_f16(af[i], bf[j], acc[i][j], 0, 0, 0);
  }

  float b2v[4];
  #pragma unroll
  for (int j = 0; j < 4; ++j) b2v[j] = b2[wc + 16*j + ln];
  float ps[4], pq[4];
  #pragma unroll
  for (int j = 0; j < 4; ++j){ ps[j] = 0.f; pq[j] = 0.f; }
  #pragma unroll
  for (int i = 0; i < 2; ++i){
    #pragma unroll
    for (int r = 0; r < 4; ++r){
      int rg = rbase + m0 + 16*i + 4*q + r;
      if (rg < NN){
        #pragma unroll
        for (int j = 0; j < 4; ++j){
          float v = acc[i][j][r] + b2v[j];
          z2[(size_t)rg*HID + wc + 16*j + ln] = v;
          ps[j] += v; pq[j] += v*v;
        }
      }
    }
  }
  red[tid] = 0.f;
  if (tid < 128) red[128 + tid] = 0.f;
  __syncthreads();
  #pragma unroll
  for (int j = 0; j < 4; ++j){
    int c = wc + 16*j + ln;
    atomicAdd(&red[c], ps[j]);
    atomicAdd(&red[128 + c], pq[j]);
  }
  __syncthreads();
  if (tid < 128){
    atomicAdd(&bnS[tid], red[tid]);
    atomicAdd(&bnQ[tid], red[128 + tid]);
  }
}

// ======================= BN apply + ReLU -> hf (f16) =======================
__global__ void kBn(const float* __restrict__ z2, const float* __restrict__ bnS,
                    const float* __restrict__ bnQ, const float* __restrict__ gamma,
                    const float* __restrict__ beta, ushort_t* __restrict__ hf){
  int gid = blockIdx.x*256 + threadIdx.x;   // NN*64
  if (gid >= NN*64) return;
  int r = gid >> 6, c = (gid & 63)*2;
  float2 zv = *(const float2*)&z2[(size_t)r*HID + c];
  float2 sS = *(const float2*)&bnS[c];
  float2 sQ = *(const float2*)&bnQ[c];
  float2 gm = *(const float2*)&gamma[c];
  float2 bt = *(const float2*)&beta[c];
  float m0 = sS.x*(1.f/NN), m1 = sS.y*(1.f/NN);
  float v0 = sQ.x*(1.f/NN) - m0*m0, v1 = sQ.y*(1.f/NN) - m1*m1;
  float o0 = fmaxf((zv.x - m0)*rsqrtf(v0 + 1e-5f)*gm.x + bt.x, 0.f);
  float o1 = fmaxf((zv.y - m1)*rsqrtf(v1 + 1e-5f)*gm.y + bt.y, 0.f);
  *(unsigned*)&hf[(size_t)r*HID + c] = pkf16(o0, o1);
}

// ======================= pool =======================
__global__ __launch_bounds__(192) void kPool(const ushort_t* __restrict__ hf, const int* __restrict__ bid,
                      const int* __restrict__ tidx, const float* __restrict__ temb,
                      float* __restrict__ g){
  int b = blockIdx.x, t = threadIdx.x;
  int lo = 0, hi = NN;
  while (lo < hi){ int m = (lo + hi) >> 1; if (bid[m] < b) lo = m + 1; else hi = m; }
  int s = lo;
  lo = 0; hi = NN;
  while (lo < hi){ int m = (lo + hi) >> 1; if (bid[m] < b + 1) lo = m + 1; else hi = m; }
  int e = lo;
  if (t < HID){
    float acc = 0.f;
    for (int n = s; n < e; ++n) acc += h2f(hf[(size_t)n*HID + t]);
    g[b*192 + t] = acc;
  } else {
    int j = t - HID;
    g[b*192 + HID + j] = temb[tidx[b]*TE + j];
  }
}

// ======================= head MLP =======================
__global__ __launch_bounds__(128) void kHead(const float* __restrict__ g,
    const float* __restrict__ w1, const float* __restrict__ b1,
    const float* __restrict__ w2, const float* __restrict__ b2,
    const float* __restrict__ w3, const float* __restrict__ b3,
    float* __restrict__ out){
  __shared__ float gv[192];
  __shared__ float t1[128];
  __shared__ float t2[64];
  int b = blockIdx.x, t = threadIdx.x;
  gv[t] = g[b*192 + t];
  if (t < 64) gv[128 + t] = g[b*192 + 128 + t];
  __syncthreads();
  float acc = b1[t];
  for (int k = 0; k < 192; ++k) acc = fmaf(gv[k], w1[k*HID + t], acc);
  t1[t] = fmaxf(acc, 0.f);
  __syncthreads();
  if (t < 64){
    float a2 = b2[t];
    for (int k = 0; k < 128; ++k) a2 = fmaf(t1[k], w2[k*64 + t], a2);
    t2[t] = fmaxf(a2, 0.f);
  }
  __syncthreads();
  if (t == 0){
    float s = b3[0];
    for (int k = 0; k < 64; ++k) s = fmaf(t2[k], w3[k], s);
    out[b] = s;
  }
}

// ======================= launch =======================
extern "C" void kernel_launch(void* const* d_in, const int* in_sizes, int n_in,
                              void* d_out, int out_size, void* d_ws, size_t ws_size,
                              hipStream_t stream){
  const float* x     = (const float*)d_in[0];
  const int*   ei    = (const int*)  d_in[1];
  const float* eattr = (const float*)d_in[2];
  const int*   bids  = (const int*)  d_in[3];
  const int*   tgt   = (const int*)  d_in[4];
  const float* nw    = (const float*)d_in[5];
  const float* nb    = (const float*)d_in[6];
  const float* eps   = (const float*)d_in[7];
  const float* ew    = (const float*)d_in[8];
  const float* eb    = (const float*)d_in[9];
  const float* w1    = (const float*)d_in[10];
  const float* bb1   = (const float*)d_in[11];
  const float* w2    = (const float*)d_in[12];
  const float* bb2   = (const float*)d_in[13];
  const float* gam   = (const float*)d_in[14];
  const float* bet   = (const float*)d_in[15];
  const float* temb  = (const float*)d_in[16];
  const float* h1w   = (const float*)d_in[17];
  const float* h1b   = (const float*)d_in[18];
  const float* h2w   = (const float*)d_in[19];
  const float* h2b   = (const float*)d_in[20];
  const float* h3w   = (const float*)d_in[21];
  const float* h3b   = (const float*)d_in[22];
  float* out = (float*)d_out;

  ushort_t* zb  = (ushort_t*)d_ws;                      // (NN+48)*128
  ushort_t* wtb = zb + (size_t)(NN + 48)*HID;           // 6*16384
  ushort_t* hf  = wtb + (size_t)6*16384;                // NN*128
  unsigned* eaPos = (unsigned*)(hf + (size_t)NN*HID);   // NE*8
  float* z2  = (float*)(eaPos + (size_t)NE*8);          // NN*128
  float* g   = z2 + (size_t)NN*HID;                     // NG*192
  float* bnS = g  + (size_t)NG*192;                     // 128
  float* bnQ = bnS + HID;                               // 128
  int* offs  = (int*)(bnQ + HID);                       // NN+1
  int* cnt   = offs + NN + 1;                           // NN
  int* curs  = cnt + NN;                                // NN
  int* perm  = curs + NN;                               // NE
  int* srcPos= perm + NE;                               // NE
  int* psum  = srcPos + NE;                             // 256
  int* pofs  = psum + 256;                              // 256

  const int* esrc = ei;
  const int* edst = ei + NE;

  kConvW   <<<(6*16384 + 48*128 + 255)/256, 256, 0, stream>>>(w1, w2, wtb, zb);
  kZero    <<<(NN + 255)/256, 256, 0, stream>>>(cnt, NN);
  kHist    <<<(NE + 255)/256, 256, 0, stream>>>(edst, cnt);
  kPartSum <<<SCAN_B, 256, 0, stream>>>(cnt, psum);
  kScanPart<<<1, 256, 0, stream>>>(psum, pofs, offs);
  kScanApply<<<SCAN_B, 256, 0, stream>>>(cnt, pofs, offs, curs);
  kScatter <<<(NE + 255)/256, 256, 0, stream>>>(edst, esrc, curs, perm, srcPos);
  kPermEA  <<<(NE*2 + 255)/256, 256, 0, stream>>>(eattr, perm, eaPos);
  kNodeInit<<<(NN*64 + 255)/256, 256, 0, stream>>>(x, nw, nb, hf);

  for (int l = 0; l < NL; ++l){
    kAgg<<<2048, 256, 0, stream>>>(hf, eaPos, srcPos, offs,
                                 ew + (size_t)l*EIN*HID, eb + (size_t)l*HID, eps, l,
                                 zb, bnS, bnQ);
    kMlp<<<(NN + BM - 1)/BM, 256, 0, stream>>>(zb, z2,
                                 wtb + (size_t)l*16384, bb1 + (size_t)l*HID,
                                 wtb + (size_t)(3+l)*16384, bb2 + (size_t)l*HID,
                                 bnS, bnQ);
    kBn<<<(NN*64 + 255)/256, 256, 0, stream>>>(z2, bnS, bnQ,
                                 gam + (size_t)l*HID, bet + (size_t)l*HID, hf);
  }

  kPool<<<NG, 192, 0, stream>>>(hf, bids, tgt, temb, g);
  kHead<<<NG, 128, 0, stream>>>(g, h1w, h1b, h2w, h2b, h3w, h3b, out);
}